// Round 20
// baseline (649.910 us; speedup 1.0000x reference)
//
#include <hip/hip_runtime.h>

// ParallelExpert: grouped SwiGLU MLP, E=8 experts.
//   h = x @ w1 ; h_act = silu(gate)*val ; out = h_act @ w2
// Round 20: gemm1 -> BM=256 (was 128). Per-wave per-K-step: 24 ds_read_b128
//   (288cyc) vs 64 MFMA (320cyc) -> MFMA-limited (was 16 reads/32 MFMA =
//   LDS-limited at 40% MfmaUtil). LDS 64KB (2 blocks/CU), acc 128 VGPR,
//   af read per-m-frag to cap liveness. w2x overlap kept (r19: -10us).
// ws layout: [0,128M) hact; [128M,256M) w1t; [256M,320M) w2t; [320M,352M) xh.

#define E_    8
#define T_    2048
#define DIN   1024
#define DHID  4096
#define DOUT  1024
#define INTER 8192

#define NB_W1   16384   // E * (DIN/64) * (INTER/64)
#define NB_CONV 2048
#define NB_G1   2048    // E * 8 * 32  (BM=256)
#define NB_X2   4096    // 8192 w2-tiles / 2 per block

typedef _Float16 f16;
typedef _Float16 f16x8 __attribute__((ext_vector_type(8)));
typedef float    f32x4 __attribute__((ext_vector_type(4)));

typedef const __attribute__((address_space(1))) void gvoid_t;
typedef __attribute__((address_space(3))) void lvoid_t;

__device__ __forceinline__ void gload_lds16(const void* g, void* l) {
  __builtin_amdgcn_global_load_lds((gvoid_t*)g, (lvoid_t*)l, 16, 0, 0);
}

// ---- device bodies for prep work ------------------------------------------
__device__ __forceinline__ void conv_body(
    const float* __restrict__ src, f16* __restrict__ dst, int n8,
    int bid, int nblk) {
  int i = bid * 256 + threadIdx.x;
  int stride = nblk * 256;
  for (; i < n8; i += stride) {
    const float4* s = (const float4*)(src + (size_t)i * 8);
    float4 a0 = s[0], a1 = s[1];
    f16x8 v;
    v[0] = (f16)a0.x; v[1] = (f16)a0.y; v[2] = (f16)a0.z; v[3] = (f16)a0.w;
    v[4] = (f16)a1.x; v[5] = (f16)a1.y; v[6] = (f16)a1.z; v[7] = (f16)a1.w;
    *(f16x8*)(dst + (size_t)i * 8) = v;
  }
}

// 256-thread-slice transpose of one 64x64 tile; t in [0,256)
__device__ __forceinline__ void xpose64_tile(
    const float* __restrict__ src, f16* __restrict__ dst,
    int R, int C, int tC, int tileIdx, f16 (*tile)[72], int t) {
  int perE = (R >> 6) * tC;
  int e = tileIdx / perE;
  int rem = tileIdx - e * perE;
  int rt = rem / tC;
  int ct = rem - rt * tC;
  int r0 = rt << 6, c0 = ct << 6;
  int lr  = t >> 2;          // 0..63
  int lc4 = (t & 3) * 16;    // 0,16,32,48
  const float* s = src + (size_t)e * R * C + (size_t)(r0 + lr) * C + c0 + lc4;
#pragma unroll
  for (int i = 0; i < 4; ++i) {
    float4 v = *(const float4*)(s + i * 4);
    tile[lr][lc4 + i * 4 + 0] = (f16)v.x;
    tile[lr][lc4 + i * 4 + 1] = (f16)v.y;
    tile[lr][lc4 + i * 4 + 2] = (f16)v.z;
    tile[lr][lc4 + i * 4 + 3] = (f16)v.w;
  }
  __syncthreads();
  f16* d = dst + (size_t)e * C * R + (size_t)(c0 + lr) * R + r0 + lc4;
  f16x8 o0, o1;
#pragma unroll
  for (int j = 0; j < 8; ++j) o0[j] = tile[lc4 + j][lr];
#pragma unroll
  for (int j = 0; j < 8; ++j) o1[j] = tile[lc4 + 8 + j][lr];
  *(f16x8*)(d)     = o0;
  *(f16x8*)(d + 8) = o1;
}

// ---- prep: [0,16384) w1-xpose | [16384,18432) x-conv ----------------------
__global__ __launch_bounds__(256) void prep_w1_conv(
    const float* __restrict__ x,  f16* __restrict__ xh,
    const float* __restrict__ w1, f16* __restrict__ w1t) {
  __shared__ f16 tile[64][72];
  int bid = blockIdx.x;
  if (bid < NB_W1) {
    xpose64_tile(w1, w1t, DIN, INTER, INTER / 64, bid, tile, threadIdx.x);
  } else {
    conv_body(x, xh, E_ * T_ * DIN / 8, bid - NB_W1, NB_CONV);
  }
}

// ---- standalone prep kernels (fallback tiers) -----------------------------
__global__ __launch_bounds__(256) void conv_f32_f16(
    const float* __restrict__ src, f16* __restrict__ dst, int n8) {
  conv_body(src, dst, n8, blockIdx.x, gridDim.x);
}

__global__ __launch_bounds__(256) void xpose64_f32_f16(
    const float* __restrict__ src, f16* __restrict__ dst,
    int R, int C, int tC) {
  __shared__ f16 tile[64][72];
  xpose64_tile(src, dst, R, C, tC, blockIdx.x, tile, threadIdx.x);
}

// ---- gemm1 BM=256 (BK=64 swizzled 2ph) + overlapped w2-xpose --------------
// blocks [0,NB_G1): gemm1; [NB_G1, NB_G1+NB_X2): w2-xpose (2 tiles/block)
__global__ __launch_bounds__(512, 2) void gemm1_swiglu_w2x(
    const f16* __restrict__ xh,
    const f16* __restrict__ w1t,
    f16* __restrict__ hact,
    const float* __restrict__ w2,
    f16* __restrict__ w2t) {
  __shared__ __align__(1024) f16 As[256][64];   // 32 KiB
  __shared__ __align__(1024) f16 Bg[128][64];   // 16 KiB
  __shared__ __align__(1024) f16 Bv[128][64];   // 16 KiB

  int bid = blockIdx.x;
  if (bid >= NB_G1) {
    // w2 transpose: two 64x64 tiles per 512-thread block, LDS aliased on As
    int half = threadIdx.x >> 8;                     // 0/1
    int t    = threadIdx.x & 255;
    int tileIdx = (bid - NB_G1) * 2 + half;
    f16 (*tile)[72] = (f16(*)[72])((char*)&As[0][0] + half * 9216);
    xpose64_tile(w2, w2t, DHID, DOUT, DOUT / 64, tileIdx, tile, t);
    return;
  }

  int e   = bid >> 8;
  int rem = bid & 255;
  int mt  = rem >> 5;          // 0..7  (M tiles of 256)
  int nt  = rem & 31;          // 0..31
  int m0 = mt * 256, n0 = nt * 128;

  const f16* xe = xh  + ((size_t)e * T_ + m0) * DIN;
  const f16* wg = w1t + ((size_t)e * INTER + n0) * DIN;
  const f16* wv = w1t + ((size_t)e * INTER + DHID + n0) * DIN;

  int tid  = threadIdx.x;
  int lane = tid & 63;
  int wid  = tid >> 6;

  int srow8 = lane >> 3;
  int scol  = ((lane & 7) ^ srow8) * 8;

  auto stA = [&](int kt, int i) {
    int ci = wid + 8 * i;  // chunk 0..31 (rows ci*8..+7)
    gload_lds16(xe + (size_t)(ci * 8 + srow8) * DIN + kt * 64 + scol,
                (char*)&As[0][0] + ci * 1024);
  };
  auto stG = [&](int kt, int i) {
    int ci = wid + 8 * i;  // chunk 0..15
    gload_lds16(wg + (size_t)(ci * 8 + srow8) * DIN + kt * 64 + scol,
                (char*)&Bg[0][0] + ci * 1024);
  };
  auto stV = [&](int kt, int i) {
    int ci = wid + 8 * i;
    gload_lds16(wv + (size_t)(ci * 8 + srow8) * DIN + kt * 64 + scol,
                (char*)&Bv[0][0] + ci * 1024);
  };

  int wm  = wid >> 2;            // 0..1 -> rows wm*128..+127
  int wn  = wid & 3;             // 0..3 -> cols wn*32..+31
  int lr  = lane & 15;
  int l16 = lane >> 4;

  f32x4 accG[8][2], accV[8][2];  // 128 VGPRs
#pragma unroll
  for (int m = 0; m < 8; ++m)
#pragma unroll
    for (int n = 0; n < 2; ++n) {
      accG[m][n] = f32x4{0.f, 0.f, 0.f, 0.f};
      accV[m][n] = f32x4{0.f, 0.f, 0.f, 0.f};
    }

  for (int kt = 0; kt < DIN / 64; ++kt) {   // 16 K-steps
    __syncthreads();
    stA(kt, 0); stA(kt, 1); stA(kt, 2); stA(kt, 3);
    stG(kt, 0); stG(kt, 1);
    stV(kt, 0); stV(kt, 1);
    __syncthreads();

    f16x8 bg[2][2], bv[2][2];
#pragma unroll
    for (int n = 0; n < 2; ++n)
#pragma unroll
      for (int kk = 0; kk < 2; ++kk) {
        int row_ = wn * 32 + n * 16 + lr;
        bg[n][kk] = *(const f16x8*)((const char*)&Bg[0][0] + row_ * 128 +
                                    (((kk * 4 + l16) ^ (lr & 7)) << 4));
        bv[n][kk] = *(const f16x8*)((const char*)&Bv[0][0] + row_ * 128 +
                                    (((kk * 4 + l16) ^ (lr & 7)) << 4));
      }
#pragma unroll
    for (int m = 0; m < 8; ++m) {
      f16x8 af[2];
#pragma unroll
      for (int kk = 0; kk < 2; ++kk) {
        int row_ = wm * 128 + m * 16 + lr;
        af[kk] = *(const f16x8*)((const char*)&As[0][0] + row_ * 128 +
                                 (((kk * 4 + l16) ^ (lr & 7)) << 4));
      }
#pragma unroll
      for (int n = 0; n < 2; ++n)
#pragma unroll
        for (int kk = 0; kk < 2; ++kk) {
          accG[m][n] = __builtin_amdgcn_mfma_f32_16x16x32_f16(af[kk], bg[n][kk], accG[m][n], 0, 0, 0);
          accV[m][n] = __builtin_amdgcn_mfma_f32_16x16x32_f16(af[kk], bv[n][kk], accV[m][n], 0, 0, 0);
        }
    }
  }

  f16* he = hact + (size_t)e * T_ * DHID;
  int rbase = m0 + wm * 128 + l16 * 4;
  int cbase = n0 + wn * 32 + lr;
#pragma unroll
  for (int m = 0; m < 8; ++m)
#pragma unroll
    for (int n = 0; n < 2; ++n)
#pragma unroll
      for (int j = 0; j < 4; ++j) {
        int row = rbase + m * 16 + j;
        int col = cbase + n * 16;
        float g = accG[m][n][j];
        float v = accV[m][n][j];
        float s = g / (1.0f + __expf(-g));
        he[(size_t)row * DHID + col] = (f16)(s * v);
      }
}

// ---- gemm1 standalone (r14 BM=128) for the non-overlap tier ---------------
__global__ __launch_bounds__(512, 2) void gemm1_swiglu_xh(
    const f16* __restrict__ xh,
    const f16* __restrict__ w1t,
    f16* __restrict__ hact) {
  __shared__ __align__(1024) f16 As[128][64];
  __shared__ __align__(1024) f16 Bg[128][64];
  __shared__ __align__(1024) f16 Bv[128][64];

  int bid = blockIdx.x;
  int e   = bid >> 9;
  int rem = bid & 511;
  int mt  = rem >> 5;
  int nt  = rem & 31;
  int m0 = mt * 128, n0 = nt * 128;

  const f16* xe = xh  + ((size_t)e * T_ + m0) * DIN;
  const f16* wg = w1t + ((size_t)e * INTER + n0) * DIN;
  const f16* wv = w1t + ((size_t)e * INTER + DHID + n0) * DIN;

  int tid  = threadIdx.x;
  int lane = tid & 63;
  int wid  = tid >> 6;

  int srow8 = lane >> 3;
  int scol  = ((lane & 7) ^ srow8) * 8;

  auto stA = [&](int kt, int i) {
    int ci = wid + 8 * i;
    gload_lds16(xe + (size_t)(ci * 8 + srow8) * DIN + kt * 64 + scol,
                (char*)&As[0][0] + ci * 1024);
  };
  auto stG = [&](int kt, int i) {
    int ci = wid + 8 * i;
    gload_lds16(wg + (size_t)(ci * 8 + srow8) * DIN + kt * 64 + scol,
                (char*)&Bg[0][0] + ci * 1024);
  };
  auto stV = [&](int kt, int i) {
    int ci = wid + 8 * i;
    gload_lds16(wv + (size_t)(ci * 8 + srow8) * DIN + kt * 64 + scol,
                (char*)&Bv[0][0] + ci * 1024);
  };

  int wm  = wid >> 2;
  int wn  = wid & 3;
  int lr  = lane & 15;
  int l16 = lane >> 4;

  f32x4 accG[4][2], accV[4][2];
#pragma unroll
  for (int m = 0; m < 4; ++m)
#pragma unroll
    for (int n = 0; n < 2; ++n) {
      accG[m][n] = f32x4{0.f, 0.f, 0.f, 0.f};
      accV[m][n] = f32x4{0.f, 0.f, 0.f, 0.f};
    }

  for (int kt = 0; kt < DIN / 64; ++kt) {
    __syncthreads();
    stA(kt, 0); stA(kt, 1);
    stG(kt, 0); stG(kt, 1);
    stV(kt, 0); stV(kt, 1);
    __syncthreads();

    f16x8 af[4][2], bg[2][2], bv[2][2];
#pragma unroll
    for (int m = 0; m < 4; ++m)
#pragma unroll
      for (int kk = 0; kk < 2; ++kk) {
        int row_ = wm * 64 + m * 16 + lr;
        af[m][kk] = *(const f16x8*)((const char*)&As[0][0] + row_ * 128 +
                                    (((kk * 4 + l16) ^ (lr & 7)) << 4));
      }
#pragma unroll
    for (int n = 0; n < 2; ++n)
#pragma unroll
      for (int kk = 0; kk < 2; ++kk) {
        int row_ = wn * 32 + n * 16 + lr;
        bg[n][kk] = *(const f16x8*)((const char*)&Bg[0][0] + row_ * 128 +
                                    (((kk * 4 + l16) ^ (lr & 7)) << 4));
        bv[n][kk] = *(const f16x8*)((const char*)&Bv[0][0] + row_ * 128 +
                                    (((kk * 4 + l16) ^ (lr & 7)) << 4));
      }
#pragma unroll
    for (int m = 0; m < 4; ++m)
#pragma unroll
      for (int n = 0; n < 2; ++n)
#pragma unroll
        for (int kk = 0; kk < 2; ++kk) {
          accG[m][n] = __builtin_amdgcn_mfma_f32_16x16x32_f16(af[m][kk], bg[n][kk], accG[m][n], 0, 0, 0);
          accV[m][n] = __builtin_amdgcn_mfma_f32_16x16x32_f16(af[m][kk], bv[n][kk], accV[m][n], 0, 0, 0);
        }
  }

  f16* he = hact + (size_t)e * T_ * DHID;
  int rbase = m0 + wm * 64 + l16 * 4;
  int cbase = n0 + wn * 32 + lr;
#pragma unroll
  for (int m = 0; m < 4; ++m)
#pragma unroll
    for (int n = 0; n < 2; ++n)
#pragma unroll
      for (int j = 0; j < 4; ++j) {
        int row = rbase + m * 16 + j;
        int col = cbase + n * 16;
        float g = accG[m][n][j];
        float v = accV[m][n][j];
        float s = g / (1.0f + __expf(-g));
        he[(size_t)row * DHID + col] = (f16)(s * v);
      }
}

// ---- GEMM1 fallback (reg-staged fp32 A), minimal tier ---------------------
__global__ __launch_bounds__(512, 2) void gemm1_swiglu_rs(
    const float* __restrict__ x,
    const f16* __restrict__ w1t,
    f16* __restrict__ hact) {
  __shared__ f16 As[128][36];
  __shared__ f16 Bg[128][32];
  __shared__ f16 Bv[128][32];

  int bid = blockIdx.x;
  int e   = bid >> 9;
  int rem = bid & 511;
  int mt  = rem >> 5;
  int nt  = rem & 31;
  int m0 = mt * 128, n0 = nt * 128;

  const float* xe = x   + ((size_t)e * T_ + m0) * DIN;
  const f16*   wg = w1t + ((size_t)e * INTER + n0) * DIN;
  const f16*   wv = w1t + ((size_t)e * INTER + DHID + n0) * DIN;

  int tid  = threadIdx.x;
  int lane = tid & 63;
  int wid  = tid >> 6;

  int arow = tid >> 2;
  int acol = (tid & 3) * 8;
  int brow = wid * 16 + (lane >> 2);
  int bcol = (lane & 3) * 8;
  f16* lG = &Bg[wid * 16][0];
  f16* lV = &Bv[wid * 16][0];

  int wm = wid >> 2;
  int wn = wid & 3;
  int lr = lane & 15;
  int lk = (lane >> 4) * 8;

  f32x4 accG[4][2], accV[4][2];
#pragma unroll
  for (int m = 0; m < 4; ++m)
#pragma unroll
    for (int n = 0; n < 2; ++n) {
      accG[m][n] = f32x4{0.f, 0.f, 0.f, 0.f};
      accV[m][n] = f32x4{0.f, 0.f, 0.f, 0.f};
    }

  for (int k = 0; k < DIN; k += 32) {
    __syncthreads();
    gload_lds16(wg + (size_t)brow * DIN + k + bcol, lG);
    gload_lds16(wv + (size_t)brow * DIN + k + bcol, lV);
    {
      const float* sa = xe + (size_t)arow * DIN + k + acol;
      float4 a0 = ((const float4*)sa)[0];
      float4 a1 = ((const float4*)sa)[1];
      f16x8 v;
      v[0] = (f16)a0.x; v[1] = (f16)a0.y; v[2] = (f16)a0.z; v[3] = (f16)a0.w;
      v[4] = (f16)a1.x; v[5] = (f16)a1.y; v[6] = (f16)a1.z; v[7] = (f16)a1.w;
      *(f16x8*)&As[arow][acol] = v;
    }
    __syncthreads();

    f16x8 af[4], bg[2], bv[2];
#pragma unroll
    for (int m = 0; m < 4; ++m)
      af[m] = *(const f16x8*)&As[wm * 64 + m * 16 + lr][lk];
#pragma unroll
    for (int n = 0; n < 2; ++n) {
      bg[n] = *(const f16x8*)&Bg[wn * 32 + n * 16 + lr][lk];
      bv[n] = *(const f16x8*)&Bv[wn * 32 + n * 16 + lr][lk];
    }
#pragma unroll
    for (int m = 0; m < 4; ++m)
#pragma unroll
      for (int n = 0; n < 2; ++n) {
        accG[m][n] = __builtin_amdgcn_mfma_f32_16x16x32_f16(af[m], bg[n], accG[m][n], 0, 0, 0);
        accV[m][n] = __builtin_amdgcn_mfma_f32_16x16x32_f16(af[m], bv[n], accV[m][n], 0, 0, 0);
      }
  }

  f16* he = hact + (size_t)e * T_ * DHID;
  int rbase = m0 + wm * 64 + (lane >> 4) * 4;
  int cbase = n0 + wn * 32 + lr;
#pragma unroll
  for (int m = 0; m < 4; ++m)
#pragma unroll
    for (int n = 0; n < 2; ++n)
#pragma unroll
      for (int j = 0; j < 4; ++j) {
        int row = rbase + m * 16 + j;
        int col = cbase + n * 16;
        float g = accG[m][n][j];
        float v = accV[m][n][j];
        float s = g / (1.0f + __expf(-g));
        he[(size_t)row * DHID + col] = (f16)(s * v);
      }
}

// ---- GEMM2, 8-phase 256x256 (K=4096 = 64 K-tiles) — r11-proven ------------
__global__ __launch_bounds__(512, 2) void gemm2_8ph(
    const f16* __restrict__ hact,
    const f16* __restrict__ w2t,
    float* __restrict__ out) {
  __shared__ __align__(1024) f16 As[2][256][64];
  __shared__ __align__(1024) f16 Bs[2][256][64];

  int bid = blockIdx.x;
  int e   = bid >> 5;
  int rem = bid & 31;
  int mt  = rem >> 2;
  int nt  = rem & 3;
  int m0 = mt * 256, n0 = nt * 256;

  const f16* ha = hact + ((size_t)e * T_ + m0) * DHID;
  const f16* wb = w2t  + ((size_t)e * DOUT + n0) * DHID;

  int tid  = threadIdx.x;
  int lane = tid & 63;
  int wid  = tid >> 6;
  int wm   = wid >> 2;
  int wn   = wid & 3;
  int lr   = lane & 15;
  int l16  = lane >> 4;

  int srow = lane >> 3;
  int scol = ((lane & 7) ^ srow) * 8;

  auto stA = [&](int buf, int kt, int i) {
    int ci = wid + 8 * i;
    gload_lds16(ha + (size_t)(ci * 8 + srow) * DHID + kt * 64 + scol,
                (char*)&As[buf][0][0] + ci * 1024);
  };
  auto stB = [&](int buf, int kt, int i) {
    int ci = wid + 8 * i;
    gload_lds16(wb + (size_t)(ci * 8 + srow) * DHID + kt * 64 + scol,
                (char*)&Bs[buf][0][0] + ci * 1024);
  };

  f32x4 acc[8][4];
#pragma unroll
  for (int m = 0; m < 8; ++m)
#pragma unroll
    for (int n = 0; n < 4; ++n) acc[m][n] = f32x4{0.f, 0.f, 0.f, 0.f};

  f16x8 af[4][2], bf0[2][2], bf1[2][2];

#define READ_A2(b, MH)                                                       \
  _Pragma("unroll") for (int m = 0; m < 4; ++m)                              \
  _Pragma("unroll") for (int kk = 0; kk < 2; ++kk) {                         \
    int row_ = wm * 128 + (MH) * 64 + m * 16 + lr;                           \
    af[m][kk] = *(const f16x8*)((const char*)&As[b][0][0] + row_ * 128 +     \
                                (((kk * 4 + l16) ^ (lr & 7)) << 4));         \
  }
#define READ_B2(b, NH, DST)                                                  \
  _Pragma("unroll") for (int n = 0; n < 2; ++n)                              \
  _Pragma("unroll") for (int kk = 0; kk < 2; ++kk) {                         \
    int row_ = wn * 64 + (NH) * 32 + n * 16 + lr;                            \
    DST[n][kk] = *(const f16x8*)((const char*)&Bs[b][0][0] + row_ * 128 +    \
                                 (((kk * 4 + l16) ^ (lr & 7)) << 4));        \
  }
#define MFMA16Q(MH, NH, BB)                                                  \
  __builtin_amdgcn_s_setprio(1);                                            \
  _Pragma("unroll") for (int m = 0; m < 4; ++m)                              \
  _Pragma("unroll") for (int n = 0; n < 2; ++n)                              \
  _Pragma("unroll") for (int kk = 0; kk < 2; ++kk)                          \
    acc[(MH) * 4 + m][(NH) * 2 + n] = __builtin_amdgcn_mfma_f32_16x16x32_f16(\
        af[m][kk], BB[n][kk], acc[(MH) * 4 + m][(NH) * 2 + n], 0, 0, 0);     \
  __builtin_amdgcn_s_setprio(0);
#define BAR() __builtin_amdgcn_s_barrier()
#define LGKM0() asm volatile("s_waitcnt lgkmcnt(0)" ::: "memory")
#define VM6() asm volatile("s_waitcnt vmcnt(6)" ::: "memory")

  stA(0, 0, 0); stA(0, 0, 1); stA(0, 0, 2); stA(0, 0, 3);
  stB(0, 0, 0); stB(0, 0, 1); stB(0, 0, 2); stB(0, 0, 3);
  stB(1, 1, 0); stB(1, 1, 1); stB(1, 1, 2); stB(1, 1, 3);
  stA(1, 1, 0); stA(1, 1, 1);
  VM6();
  BAR();

  for (int it = 0; it < 32; ++it) {
    int tb = 2 * it + 1;
    int pa = (2 * it + 2) & 63;
    int pb = (2 * it + 3) & 63;

    READ_A2(0, 0); READ_B2(0, 0, bf0);
    stA(1, tb, 2); stA(1, tb, 3);
    BAR(); LGKM0();
    MFMA16Q(0, 0, bf0);
    BAR();

    READ_B2(0, 1, bf1);
    BAR(); LGKM0();
    MFMA16Q(0, 1, bf1);
    BAR();

    READ_A2(0, 1);
    stB(0, pa, 0); stB(0, pa, 1);
    BAR(); LGKM0();
    MFMA16Q(1, 0, bf0);
    BAR();

    stB(0, pa, 2); stB(0, pa, 3);
    stA(0, pa, 0); stA(0, pa, 1);
    BAR();
    MFMA16Q(1, 1, bf1);
    VM6();
    BAR();

    READ_A2(1, 0); READ_B2(1, 0, bf0);
    stA(0, pa, 2); stA(0, pa, 3);
    BAR(); LGKM0();
    MFMA16Q(0, 0, bf0);
    BAR();

    READ_B2(1, 1, bf1);
    BAR(); LGKM0();
    MFMA16Q(0, 1, bf1);
    BAR();

    READ_A2(1, 1);
    stB(1, pb, 0); stB(1, pb, 1);
    BAR(); LGKM0();
    MFMA16Q(1, 0, bf0);
    BAR();

    stB(1, pb, 2); stB(1, pb, 3);
    stA(1, pb, 0); stA(1, pb, 1);
    BAR();
    MFMA16Q(1, 1, bf1);
    VM6();
    BAR();
  }

#undef READ_A2
#undef READ_B2
#undef MFMA16Q
#undef BAR
#undef LGKM0
#undef VM6

  float* oe = out + (size_t)e * T_ * DOUT;
  int rbase = m0 + wm * 128 + l16 * 4;
  int cbase = n0 + wn * 64 + lr;
#pragma unroll
  for (int m = 0; m < 8; ++m)
#pragma unroll
    for (int n = 0; n < 4; ++n)
#pragma unroll
      for (int j = 0; j < 4; ++j) {
        int row = rbase + m * 16 + j;
        int col = cbase + n * 16;
        oe[(size_t)row * DOUT + col] = acc[m][n][j];
      }
}

extern "C" void kernel_launch(void* const* d_in, const int* in_sizes, int n_in,
                              void* d_out, int out_size, void* d_ws, size_t ws_size,
                              hipStream_t stream) {
  const float* x  = (const float*)d_in[0];
  const float* w1 = (const float*)d_in[1];
  const float* w2 = (const float*)d_in[2];
  float* out = (float*)d_out;

  const size_t HACT_B = (size_t)E_ * T_ * DHID * 2;    // 128 MB
  const size_t W1T_B  = (size_t)E_ * INTER * DIN * 2;  // 128 MB
  const size_t W2T_B  = (size_t)E_ * DOUT * DHID * 2;  //  64 MB
  const size_t XH_B   = (size_t)E_ * T_ * DIN * 2;     //  32 MB

  f16* hact = (f16*)d_ws;
  f16* w1t  = (f16*)((char*)d_ws + HACT_B);

  if (ws_size >= HACT_B + W1T_B + W2T_B + XH_B) {
    // overlap tier: w2-xpose hidden under gemm1 (BM=256)
    f16* w2t = (f16*)((char*)d_ws + HACT_B + W1T_B);
    f16* xxh = (f16*)((char*)d_ws + HACT_B + W1T_B + W2T_B);
    prep_w1_conv<<<NB_W1 + NB_CONV, 256, 0, stream>>>(x, xxh, w1, w1t);
    gemm1_swiglu_w2x<<<NB_G1 + NB_X2, 512, 0, stream>>>(
        xxh, w1t, hact, w2, w2t);
    gemm2_8ph<<<E_ * 8 * 4, 512, 0, stream>>>(hact, w2t, out);
  } else if (ws_size >= HACT_B + W1T_B + XH_B) {
    // r14 tier: w2t aliases w1t (serialized around gemm1)
    f16* xxh = (f16*)((char*)d_ws + HACT_B + W1T_B);
    xpose64_f32_f16<<<E_ * (DIN / 64) * (INTER / 64), 256, 0, stream>>>(
        w1, w1t, DIN, INTER, INTER / 64);
    conv_f32_f16<<<2048, 256, 0, stream>>>(x, xxh, E_ * T_ * DIN / 8);
    gemm1_swiglu_xh<<<E_ * 16 * 32, 512, 0, stream>>>(xxh, w1t, hact);
    xpose64_f32_f16<<<E_ * (DHID / 64) * (DOUT / 64), 256, 0, stream>>>(
        w2, w1t, DHID, DOUT, DOUT / 64);
    gemm2_8ph<<<E_ * 8 * 4, 512, 0, stream>>>(hact, w1t, out);
  } else {
    // minimal tier: reg-staged fp32 A
    xpose64_f32_f16<<<E_ * (DIN / 64) * (INTER / 64), 256, 0, stream>>>(
        w1, w1t, DIN, INTER, INTER / 64);
    gemm1_swiglu_rs<<<E_ * 16 * 32, 512, 0, stream>>>(x, w1t, hact);
    xpose64_f32_f16<<<E_ * (DHID / 64) * (DOUT / 64), 256, 0, stream>>>(
        w2, w1t, DHID, DOUT, DOUT / 64);
    gemm2_8ph<<<E_ * 8 * 4, 512, 0, stream>>>(hact, w1t, out);
  }
}

// Round 21
// 555.690 us; speedup vs baseline: 1.1696x; 1.1696x over previous
//
#include <hip/hip_runtime.h>

// ParallelExpert: grouped SwiGLU MLP, E=8 experts.
//   h = x @ w1 ; h_act = silu(gate)*val ; out = h_act @ w2
// Round 21: REVERT to r19 (best measured 556.5us). r20's BM=256 dropped to
//   1 block/CU (occ 23%) -> barrier drains exposed -> 463us. Rule learned:
//   in the 2-barrier structure, >=2 blocks/CU beats any per-block
//   arithmetic-intensity gain (r9/r12/r20 all confirm).
// gemm1: BM=128 BK=64 swizzled 2ph (~864 TF = m248-reference-class for
//   grouped K=1024) + w2-xpose overlap. gemm2: 8-phase 256^2 (~1.45 PF).
// ws layout: [0,128M) hact; [128M,256M) w1t; [256M,320M) w2t; [320M,352M) xh.

#define E_    8
#define T_    2048
#define DIN   1024
#define DHID  4096
#define DOUT  1024
#define INTER 8192

#define NB_W1   16384   // E * (DIN/64) * (INTER/64)
#define NB_CONV 2048
#define NB_G1   4096    // E * 16 * 32  (BM=128)
#define NB_X2   4096    // 8192 w2-tiles / 2 per block

typedef _Float16 f16;
typedef _Float16 f16x8 __attribute__((ext_vector_type(8)));
typedef float    f32x4 __attribute__((ext_vector_type(4)));

typedef const __attribute__((address_space(1))) void gvoid_t;
typedef __attribute__((address_space(3))) void lvoid_t;

__device__ __forceinline__ void gload_lds16(const void* g, void* l) {
  __builtin_amdgcn_global_load_lds((gvoid_t*)g, (lvoid_t*)l, 16, 0, 0);
}

// ---- device bodies for prep work ------------------------------------------
__device__ __forceinline__ void conv_body(
    const float* __restrict__ src, f16* __restrict__ dst, int n8,
    int bid, int nblk) {
  int i = bid * 256 + threadIdx.x;
  int stride = nblk * 256;
  for (; i < n8; i += stride) {
    const float4* s = (const float4*)(src + (size_t)i * 8);
    float4 a0 = s[0], a1 = s[1];
    f16x8 v;
    v[0] = (f16)a0.x; v[1] = (f16)a0.y; v[2] = (f16)a0.z; v[3] = (f16)a0.w;
    v[4] = (f16)a1.x; v[5] = (f16)a1.y; v[6] = (f16)a1.z; v[7] = (f16)a1.w;
    *(f16x8*)(dst + (size_t)i * 8) = v;
  }
}

// 256-thread-slice transpose of one 64x64 tile; t in [0,256)
__device__ __forceinline__ void xpose64_tile(
    const float* __restrict__ src, f16* __restrict__ dst,
    int R, int C, int tC, int tileIdx, f16 (*tile)[72], int t) {
  int perE = (R >> 6) * tC;
  int e = tileIdx / perE;
  int rem = tileIdx - e * perE;
  int rt = rem / tC;
  int ct = rem - rt * tC;
  int r0 = rt << 6, c0 = ct << 6;
  int lr  = t >> 2;          // 0..63
  int lc4 = (t & 3) * 16;    // 0,16,32,48
  const float* s = src + (size_t)e * R * C + (size_t)(r0 + lr) * C + c0 + lc4;
#pragma unroll
  for (int i = 0; i < 4; ++i) {
    float4 v = *(const float4*)(s + i * 4);
    tile[lr][lc4 + i * 4 + 0] = (f16)v.x;
    tile[lr][lc4 + i * 4 + 1] = (f16)v.y;
    tile[lr][lc4 + i * 4 + 2] = (f16)v.z;
    tile[lr][lc4 + i * 4 + 3] = (f16)v.w;
  }
  __syncthreads();
  f16* d = dst + (size_t)e * C * R + (size_t)(c0 + lr) * R + r0 + lc4;
  f16x8 o0, o1;
#pragma unroll
  for (int j = 0; j < 8; ++j) o0[j] = tile[lc4 + j][lr];
#pragma unroll
  for (int j = 0; j < 8; ++j) o1[j] = tile[lc4 + 8 + j][lr];
  *(f16x8*)(d)     = o0;
  *(f16x8*)(d + 8) = o1;
}

// ---- prep: [0,16384) w1-xpose | [16384,18432) x-conv ----------------------
__global__ __launch_bounds__(256) void prep_w1_conv(
    const float* __restrict__ x,  f16* __restrict__ xh,
    const float* __restrict__ w1, f16* __restrict__ w1t) {
  __shared__ f16 tile[64][72];
  int bid = blockIdx.x;
  if (bid < NB_W1) {
    xpose64_tile(w1, w1t, DIN, INTER, INTER / 64, bid, tile, threadIdx.x);
  } else {
    conv_body(x, xh, E_ * T_ * DIN / 8, bid - NB_W1, NB_CONV);
  }
}

// ---- standalone prep kernels (fallback tiers) -----------------------------
__global__ __launch_bounds__(256) void conv_f32_f16(
    const float* __restrict__ src, f16* __restrict__ dst, int n8) {
  conv_body(src, dst, n8, blockIdx.x, gridDim.x);
}

__global__ __launch_bounds__(256) void xpose64_f32_f16(
    const float* __restrict__ src, f16* __restrict__ dst,
    int R, int C, int tC) {
  __shared__ f16 tile[64][72];
  xpose64_tile(src, dst, R, C, tC, blockIdx.x, tile, threadIdx.x);
}

// ---- gemm1 (BM=128, BK=64 swizzled 2ph) + overlapped w2-xpose -------------
// blocks [0,NB_G1): gemm1; [NB_G1, NB_G1+NB_X2): w2-xpose (2 tiles/block)
__global__ __launch_bounds__(512, 2) void gemm1_swiglu_w2x(
    const f16* __restrict__ xh,
    const f16* __restrict__ w1t,
    f16* __restrict__ hact,
    const float* __restrict__ w2,
    f16* __restrict__ w2t) {
  __shared__ __align__(1024) f16 As[128][64];
  __shared__ __align__(1024) f16 Bg[128][64];
  __shared__ __align__(1024) f16 Bv[128][64];

  int bid = blockIdx.x;
  if (bid >= NB_G1) {
    // w2 transpose: two 64x64 tiles per 512-thread block, LDS aliased on As
    int half = threadIdx.x >> 8;                     // 0/1
    int t    = threadIdx.x & 255;
    int tileIdx = (bid - NB_G1) * 2 + half;
    f16 (*tile)[72] = (f16(*)[72])((char*)&As[0][0] + half * 9216);
    xpose64_tile(w2, w2t, DHID, DOUT, DOUT / 64, tileIdx, tile, t);
    return;
  }

  int e   = bid >> 9;
  int rem = bid & 511;
  int mt  = rem >> 5;
  int nt  = rem & 31;
  int m0 = mt * 128, n0 = nt * 128;

  const f16* xe = xh  + ((size_t)e * T_ + m0) * DIN;
  const f16* wg = w1t + ((size_t)e * INTER + n0) * DIN;
  const f16* wv = w1t + ((size_t)e * INTER + DHID + n0) * DIN;

  int tid  = threadIdx.x;
  int lane = tid & 63;
  int wid  = tid >> 6;

  int srow8 = lane >> 3;
  int scol  = ((lane & 7) ^ srow8) * 8;

  auto stA = [&](int kt, int i) {
    int ci = wid + 8 * i;
    gload_lds16(xe + (size_t)(ci * 8 + srow8) * DIN + kt * 64 + scol,
                (char*)&As[0][0] + ci * 1024);
  };
  auto stG = [&](int kt, int i) {
    int ci = wid + 8 * i;
    gload_lds16(wg + (size_t)(ci * 8 + srow8) * DIN + kt * 64 + scol,
                (char*)&Bg[0][0] + ci * 1024);
  };
  auto stV = [&](int kt, int i) {
    int ci = wid + 8 * i;
    gload_lds16(wv + (size_t)(ci * 8 + srow8) * DIN + kt * 64 + scol,
                (char*)&Bv[0][0] + ci * 1024);
  };

  int wm  = wid >> 2;
  int wn  = wid & 3;
  int lr  = lane & 15;
  int l16 = lane >> 4;

  f32x4 accG[4][2], accV[4][2];
#pragma unroll
  for (int m = 0; m < 4; ++m)
#pragma unroll
    for (int n = 0; n < 2; ++n) {
      accG[m][n] = f32x4{0.f, 0.f, 0.f, 0.f};
      accV[m][n] = f32x4{0.f, 0.f, 0.f, 0.f};
    }

  for (int kt = 0; kt < DIN / 64; ++kt) {
    __syncthreads();
    stA(kt, 0); stA(kt, 1);
    stG(kt, 0); stG(kt, 1);
    stV(kt, 0); stV(kt, 1);
    __syncthreads();

    f16x8 af[4][2], bg[2][2], bv[2][2];
#pragma unroll
    for (int m = 0; m < 4; ++m)
#pragma unroll
      for (int kk = 0; kk < 2; ++kk) {
        int row_ = wm * 64 + m * 16 + lr;
        af[m][kk] = *(const f16x8*)((const char*)&As[0][0] + row_ * 128 +
                                    (((kk * 4 + l16) ^ (lr & 7)) << 4));
      }
#pragma unroll
    for (int n = 0; n < 2; ++n)
#pragma unroll
      for (int kk = 0; kk < 2; ++kk) {
        int row_ = wn * 32 + n * 16 + lr;
        bg[n][kk] = *(const f16x8*)((const char*)&Bg[0][0] + row_ * 128 +
                                    (((kk * 4 + l16) ^ (lr & 7)) << 4));
        bv[n][kk] = *(const f16x8*)((const char*)&Bv[0][0] + row_ * 128 +
                                    (((kk * 4 + l16) ^ (lr & 7)) << 4));
      }
#pragma unroll
    for (int m = 0; m < 4; ++m)
#pragma unroll
      for (int n = 0; n < 2; ++n)
#pragma unroll
        for (int kk = 0; kk < 2; ++kk) {
          accG[m][n] = __builtin_amdgcn_mfma_f32_16x16x32_f16(af[m][kk], bg[n][kk], accG[m][n], 0, 0, 0);
          accV[m][n] = __builtin_amdgcn_mfma_f32_16x16x32_f16(af[m][kk], bv[n][kk], accV[m][n], 0, 0, 0);
        }
  }

  f16* he = hact + (size_t)e * T_ * DHID;
  int rbase = m0 + wm * 64 + l16 * 4;
  int cbase = n0 + wn * 32 + lr;
#pragma unroll
  for (int m = 0; m < 4; ++m)
#pragma unroll
    for (int n = 0; n < 2; ++n)
#pragma unroll
      for (int j = 0; j < 4; ++j) {
        int row = rbase + m * 16 + j;
        int col = cbase + n * 16;
        float g = accG[m][n][j];
        float v = accV[m][n][j];
        float s = g / (1.0f + __expf(-g));
        he[(size_t)row * DHID + col] = (f16)(s * v);
      }
}

// ---- gemm1 standalone (r14) for the non-overlap tier ----------------------
__global__ __launch_bounds__(512, 2) void gemm1_swiglu_xh(
    const f16* __restrict__ xh,
    const f16* __restrict__ w1t,
    f16* __restrict__ hact) {
  __shared__ __align__(1024) f16 As[128][64];
  __shared__ __align__(1024) f16 Bg[128][64];
  __shared__ __align__(1024) f16 Bv[128][64];

  int bid = blockIdx.x;
  int e   = bid >> 9;
  int rem = bid & 511;
  int mt  = rem >> 5;
  int nt  = rem & 31;
  int m0 = mt * 128, n0 = nt * 128;

  const f16* xe = xh  + ((size_t)e * T_ + m0) * DIN;
  const f16* wg = w1t + ((size_t)e * INTER + n0) * DIN;
  const f16* wv = w1t + ((size_t)e * INTER + DHID + n0) * DIN;

  int tid  = threadIdx.x;
  int lane = tid & 63;
  int wid  = tid >> 6;

  int srow8 = lane >> 3;
  int scol  = ((lane & 7) ^ srow8) * 8;

  auto stA = [&](int kt, int i) {
    int ci = wid + 8 * i;
    gload_lds16(xe + (size_t)(ci * 8 + srow8) * DIN + kt * 64 + scol,
                (char*)&As[0][0] + ci * 1024);
  };
  auto stG = [&](int kt, int i) {
    int ci = wid + 8 * i;
    gload_lds16(wg + (size_t)(ci * 8 + srow8) * DIN + kt * 64 + scol,
                (char*)&Bg[0][0] + ci * 1024);
  };
  auto stV = [&](int kt, int i) {
    int ci = wid + 8 * i;
    gload_lds16(wv + (size_t)(ci * 8 + srow8) * DIN + kt * 64 + scol,
                (char*)&Bv[0][0] + ci * 1024);
  };

  int wm  = wid >> 2;
  int wn  = wid & 3;
  int lr  = lane & 15;
  int l16 = lane >> 4;

  f32x4 accG[4][2], accV[4][2];
#pragma unroll
  for (int m = 0; m < 4; ++m)
#pragma unroll
    for (int n = 0; n < 2; ++n) {
      accG[m][n] = f32x4{0.f, 0.f, 0.f, 0.f};
      accV[m][n] = f32x4{0.f, 0.f, 0.f, 0.f};
    }

  for (int kt = 0; kt < DIN / 64; ++kt) {
    __syncthreads();
    stA(kt, 0); stA(kt, 1);
    stG(kt, 0); stG(kt, 1);
    stV(kt, 0); stV(kt, 1);
    __syncthreads();

    f16x8 af[4][2], bg[2][2], bv[2][2];
#pragma unroll
    for (int m = 0; m < 4; ++m)
#pragma unroll
      for (int kk = 0; kk < 2; ++kk) {
        int row_ = wm * 64 + m * 16 + lr;
        af[m][kk] = *(const f16x8*)((const char*)&As[0][0] + row_ * 128 +
                                    (((kk * 4 + l16) ^ (lr & 7)) << 4));
      }
#pragma unroll
    for (int n = 0; n < 2; ++n)
#pragma unroll
      for (int kk = 0; kk < 2; ++kk) {
        int row_ = wn * 32 + n * 16 + lr;
        bg[n][kk] = *(const f16x8*)((const char*)&Bg[0][0] + row_ * 128 +
                                    (((kk * 4 + l16) ^ (lr & 7)) << 4));
        bv[n][kk] = *(const f16x8*)((const char*)&Bv[0][0] + row_ * 128 +
                                    (((kk * 4 + l16) ^ (lr & 7)) << 4));
      }
#pragma unroll
    for (int m = 0; m < 4; ++m)
#pragma unroll
      for (int n = 0; n < 2; ++n)
#pragma unroll
        for (int kk = 0; kk < 2; ++kk) {
          accG[m][n] = __builtin_amdgcn_mfma_f32_16x16x32_f16(af[m][kk], bg[n][kk], accG[m][n], 0, 0, 0);
          accV[m][n] = __builtin_amdgcn_mfma_f32_16x16x32_f16(af[m][kk], bv[n][kk], accV[m][n], 0, 0, 0);
        }
  }

  f16* he = hact + (size_t)e * T_ * DHID;
  int rbase = m0 + wm * 64 + l16 * 4;
  int cbase = n0 + wn * 32 + lr;
#pragma unroll
  for (int m = 0; m < 4; ++m)
#pragma unroll
    for (int n = 0; n < 2; ++n)
#pragma unroll
      for (int j = 0; j < 4; ++j) {
        int row = rbase + m * 16 + j;
        int col = cbase + n * 16;
        float g = accG[m][n][j];
        float v = accV[m][n][j];
        float s = g / (1.0f + __expf(-g));
        he[(size_t)row * DHID + col] = (f16)(s * v);
      }
}

// ---- GEMM1 fallback (reg-staged fp32 A), minimal tier ---------------------
__global__ __launch_bounds__(512, 2) void gemm1_swiglu_rs(
    const float* __restrict__ x,
    const f16* __restrict__ w1t,
    f16* __restrict__ hact) {
  __shared__ f16 As[128][36];
  __shared__ f16 Bg[128][32];
  __shared__ f16 Bv[128][32];

  int bid = blockIdx.x;
  int e   = bid >> 9;
  int rem = bid & 511;
  int mt  = rem >> 5;
  int nt  = rem & 31;
  int m0 = mt * 128, n0 = nt * 128;

  const float* xe = x   + ((size_t)e * T_ + m0) * DIN;
  const f16*   wg = w1t + ((size_t)e * INTER + n0) * DIN;
  const f16*   wv = w1t + ((size_t)e * INTER + DHID + n0) * DIN;

  int tid  = threadIdx.x;
  int lane = tid & 63;
  int wid  = tid >> 6;

  int arow = tid >> 2;
  int acol = (tid & 3) * 8;
  int brow = wid * 16 + (lane >> 2);
  int bcol = (lane & 3) * 8;
  f16* lG = &Bg[wid * 16][0];
  f16* lV = &Bv[wid * 16][0];

  int wm = wid >> 2;
  int wn = wid & 3;
  int lr = lane & 15;
  int lk = (lane >> 4) * 8;

  f32x4 accG[4][2], accV[4][2];
#pragma unroll
  for (int m = 0; m < 4; ++m)
#pragma unroll
    for (int n = 0; n < 2; ++n) {
      accG[m][n] = f32x4{0.f, 0.f, 0.f, 0.f};
      accV[m][n] = f32x4{0.f, 0.f, 0.f, 0.f};
    }

  for (int k = 0; k < DIN; k += 32) {
    __syncthreads();
    gload_lds16(wg + (size_t)brow * DIN + k + bcol, lG);
    gload_lds16(wv + (size_t)brow * DIN + k + bcol, lV);
    {
      const float* sa = xe + (size_t)arow * DIN + k + acol;
      float4 a0 = ((const float4*)sa)[0];
      float4 a1 = ((const float4*)sa)[1];
      f16x8 v;
      v[0] = (f16)a0.x; v[1] = (f16)a0.y; v[2] = (f16)a0.z; v[3] = (f16)a0.w;
      v[4] = (f16)a1.x; v[5] = (f16)a1.y; v[6] = (f16)a1.z; v[7] = (f16)a1.w;
      *(f16x8*)&As[arow][acol] = v;
    }
    __syncthreads();

    f16x8 af[4], bg[2], bv[2];
#pragma unroll
    for (int m = 0; m < 4; ++m)
      af[m] = *(const f16x8*)&As[wm * 64 + m * 16 + lr][lk];
#pragma unroll
    for (int n = 0; n < 2; ++n) {
      bg[n] = *(const f16x8*)&Bg[wn * 32 + n * 16 + lr][lk];
      bv[n] = *(const f16x8*)&Bv[wn * 32 + n * 16 + lr][lk];
    }
#pragma unroll
    for (int m = 0; m < 4; ++m)
#pragma unroll
      for (int n = 0; n < 2; ++n) {
        accG[m][n] = __builtin_amdgcn_mfma_f32_16x16x32_f16(af[m], bg[n], accG[m][n], 0, 0, 0);
        accV[m][n] = __builtin_amdgcn_mfma_f32_16x16x32_f16(af[m], bv[n], accV[m][n], 0, 0, 0);
      }
  }

  f16* he = hact + (size_t)e * T_ * DHID;
  int rbase = m0 + wm * 64 + (lane >> 4) * 4;
  int cbase = n0 + wn * 32 + lr;
#pragma unroll
  for (int m = 0; m < 4; ++m)
#pragma unroll
    for (int n = 0; n < 2; ++n)
#pragma unroll
      for (int j = 0; j < 4; ++j) {
        int row = rbase + m * 16 + j;
        int col = cbase + n * 16;
        float g = accG[m][n][j];
        float v = accV[m][n][j];
        float s = g / (1.0f + __expf(-g));
        he[(size_t)row * DHID + col] = (f16)(s * v);
      }
}

// ---- GEMM2, 8-phase 256x256 (K=4096 = 64 K-tiles) — r11-proven ------------
__global__ __launch_bounds__(512, 2) void gemm2_8ph(
    const f16* __restrict__ hact,
    const f16* __restrict__ w2t,
    float* __restrict__ out) {
  __shared__ __align__(1024) f16 As[2][256][64];
  __shared__ __align__(1024) f16 Bs[2][256][64];

  int bid = blockIdx.x;
  int e   = bid >> 5;
  int rem = bid & 31;
  int mt  = rem >> 2;
  int nt  = rem & 3;
  int m0 = mt * 256, n0 = nt * 256;

  const f16* ha = hact + ((size_t)e * T_ + m0) * DHID;
  const f16* wb = w2t  + ((size_t)e * DOUT + n0) * DHID;

  int tid  = threadIdx.x;
  int lane = tid & 63;
  int wid  = tid >> 6;
  int wm   = wid >> 2;
  int wn   = wid & 3;
  int lr   = lane & 15;
  int l16  = lane >> 4;

  int srow = lane >> 3;
  int scol = ((lane & 7) ^ srow) * 8;

  auto stA = [&](int buf, int kt, int i) {
    int ci = wid + 8 * i;
    gload_lds16(ha + (size_t)(ci * 8 + srow) * DHID + kt * 64 + scol,
                (char*)&As[buf][0][0] + ci * 1024);
  };
  auto stB = [&](int buf, int kt, int i) {
    int ci = wid + 8 * i;
    gload_lds16(wb + (size_t)(ci * 8 + srow) * DHID + kt * 64 + scol,
                (char*)&Bs[buf][0][0] + ci * 1024);
  };

  f32x4 acc[8][4];
#pragma unroll
  for (int m = 0; m < 8; ++m)
#pragma unroll
    for (int n = 0; n < 4; ++n) acc[m][n] = f32x4{0.f, 0.f, 0.f, 0.f};

  f16x8 af[4][2], bf0[2][2], bf1[2][2];

#define READ_A2(b, MH)                                                       \
  _Pragma("unroll") for (int m = 0; m < 4; ++m)                              \
  _Pragma("unroll") for (int kk = 0; kk < 2; ++kk) {                         \
    int row_ = wm * 128 + (MH) * 64 + m * 16 + lr;                           \
    af[m][kk] = *(const f16x8*)((const char*)&As[b][0][0] + row_ * 128 +     \
                                (((kk * 4 + l16) ^ (lr & 7)) << 4));         \
  }
#define READ_B2(b, NH, DST)                                                  \
  _Pragma("unroll") for (int n = 0; n < 2; ++n)                              \
  _Pragma("unroll") for (int kk = 0; kk < 2; ++kk) {                         \
    int row_ = wn * 64 + (NH) * 32 + n * 16 + lr;                            \
    DST[n][kk] = *(const f16x8*)((const char*)&Bs[b][0][0] + row_ * 128 +    \
                                 (((kk * 4 + l16) ^ (lr & 7)) << 4));        \
  }
#define MFMA16Q(MH, NH, BB)                                                  \
  __builtin_amdgcn_s_setprio(1);                                            \
  _Pragma("unroll") for (int m = 0; m < 4; ++m)                              \
  _Pragma("unroll") for (int n = 0; n < 2; ++n)                              \
  _Pragma("unroll") for (int kk = 0; kk < 2; ++kk)                          \
    acc[(MH) * 4 + m][(NH) * 2 + n] = __builtin_amdgcn_mfma_f32_16x16x32_f16(\
        af[m][kk], BB[n][kk], acc[(MH) * 4 + m][(NH) * 2 + n], 0, 0, 0);     \
  __builtin_amdgcn_s_setprio(0);
#define BAR() __builtin_amdgcn_s_barrier()
#define LGKM0() asm volatile("s_waitcnt lgkmcnt(0)" ::: "memory")
#define VM6() asm volatile("s_waitcnt vmcnt(6)" ::: "memory")

  stA(0, 0, 0); stA(0, 0, 1); stA(0, 0, 2); stA(0, 0, 3);
  stB(0, 0, 0); stB(0, 0, 1); stB(0, 0, 2); stB(0, 0, 3);
  stB(1, 1, 0); stB(1, 1, 1); stB(1, 1, 2); stB(1, 1, 3);
  stA(1, 1, 0); stA(1, 1, 1);
  VM6();
  BAR();

  for (int it = 0; it < 32; ++it) {
    int tb = 2 * it + 1;
    int pa = (2 * it + 2) & 63;
    int pb = (2 * it + 3) & 63;

    READ_A2(0, 0); READ_B2(0, 0, bf0);
    stA(1, tb, 2); stA(1, tb, 3);
    BAR(); LGKM0();
    MFMA16Q(0, 0, bf0);
    BAR();

    READ_B2(0, 1, bf1);
    BAR(); LGKM0();
    MFMA16Q(0, 1, bf1);
    BAR();

    READ_A2(0, 1);
    stB(0, pa, 0); stB(0, pa, 1);
    BAR(); LGKM0();
    MFMA16Q(1, 0, bf0);
    BAR();

    stB(0, pa, 2); stB(0, pa, 3);
    stA(0, pa, 0); stA(0, pa, 1);
    BAR();
    MFMA16Q(1, 1, bf1);
    VM6();
    BAR();

    READ_A2(1, 0); READ_B2(1, 0, bf0);
    stA(0, pa, 2); stA(0, pa, 3);
    BAR(); LGKM0();
    MFMA16Q(0, 0, bf0);
    BAR();

    READ_B2(1, 1, bf1);
    BAR(); LGKM0();
    MFMA16Q(0, 1, bf1);
    BAR();

    READ_A2(1, 1);
    stB(1, pb, 0); stB(1, pb, 1);
    BAR(); LGKM0();
    MFMA16Q(1, 0, bf0);
    BAR();

    stB(1, pb, 2); stB(1, pb, 3);
    stA(1, pb, 0); stA(1, pb, 1);
    BAR();
    MFMA16Q(1, 1, bf1);
    VM6();
    BAR();
  }

#undef READ_A2
#undef READ_B2
#undef MFMA16Q
#undef BAR
#undef LGKM0
#undef VM6

  float* oe = out + (size_t)e * T_ * DOUT;
  int rbase = m0 + wm * 128 + l16 * 4;
  int cbase = n0 + wn * 64 + lr;
#pragma unroll
  for (int m = 0; m < 8; ++m)
#pragma unroll
    for (int n = 0; n < 4; ++n)
#pragma unroll
      for (int j = 0; j < 4; ++j) {
        int row = rbase + m * 16 + j;
        int col = cbase + n * 16;
        oe[(size_t)row * DOUT + col] = acc[m][n][j];
      }
}

extern "C" void kernel_launch(void* const* d_in, const int* in_sizes, int n_in,
                              void* d_out, int out_size, void* d_ws, size_t ws_size,
                              hipStream_t stream) {
  const float* x  = (const float*)d_in[0];
  const float* w1 = (const float*)d_in[1];
  const float* w2 = (const float*)d_in[2];
  float* out = (float*)d_out;

  const size_t HACT_B = (size_t)E_ * T_ * DHID * 2;    // 128 MB
  const size_t W1T_B  = (size_t)E_ * INTER * DIN * 2;  // 128 MB
  const size_t W2T_B  = (size_t)E_ * DOUT * DHID * 2;  //  64 MB
  const size_t XH_B   = (size_t)E_ * T_ * DIN * 2;     //  32 MB

  f16* hact = (f16*)d_ws;
  f16* w1t  = (f16*)((char*)d_ws + HACT_B);

  if (ws_size >= HACT_B + W1T_B + W2T_B + XH_B) {
    // overlap tier: w2-xpose hidden under gemm1
    f16* w2t = (f16*)((char*)d_ws + HACT_B + W1T_B);
    f16* xxh = (f16*)((char*)d_ws + HACT_B + W1T_B + W2T_B);
    prep_w1_conv<<<NB_W1 + NB_CONV, 256, 0, stream>>>(x, xxh, w1, w1t);
    gemm1_swiglu_w2x<<<NB_G1 + NB_X2, 512, 0, stream>>>(
        xxh, w1t, hact, w2, w2t);
    gemm2_8ph<<<E_ * 8 * 4, 512, 0, stream>>>(hact, w2t, out);
  } else if (ws_size >= HACT_B + W1T_B + XH_B) {
    // r14 tier: w2t aliases w1t (serialized around gemm1)
    f16* xxh = (f16*)((char*)d_ws + HACT_B + W1T_B);
    xpose64_f32_f16<<<E_ * (DIN / 64) * (INTER / 64), 256, 0, stream>>>(
        w1, w1t, DIN, INTER, INTER / 64);
    conv_f32_f16<<<2048, 256, 0, stream>>>(x, xxh, E_ * T_ * DIN / 8);
    gemm1_swiglu_xh<<<E_ * 16 * 32, 512, 0, stream>>>(xxh, w1t, hact);
    xpose64_f32_f16<<<E_ * (DHID / 64) * (DOUT / 64), 256, 0, stream>>>(
        w2, w1t, DHID, DOUT, DOUT / 64);
    gemm2_8ph<<<E_ * 8 * 4, 512, 0, stream>>>(hact, w1t, out);
  } else {
    // minimal tier: reg-staged fp32 A
    xpose64_f32_f16<<<E_ * (DIN / 64) * (INTER / 64), 256, 0, stream>>>(
        w1, w1t, DIN, INTER, INTER / 64);
    gemm1_swiglu_rs<<<E_ * 16 * 32, 512, 0, stream>>>(x, w1t, hact);
    xpose64_f32_f16<<<E_ * (DHID / 64) * (DOUT / 64), 256, 0, stream>>>(
        w2, w1t, DHID, DOUT, DOUT / 64);
    gemm2_8ph<<<E_ * 8 * 4, 512, 0, stream>>>(hact, w1t, out);
  }
}